// Round 6
// baseline (7098.793 us; speedup 1.0000x reference)
//
#include <hip/hip_runtime.h>
#include <hip/hip_cooperative_groups.h>
#include <cmath>

namespace cg = cooperative_groups;

#define IN_DIM 1024
#define HD 256
#define G4H 1024
#define BB 64
#define TT 512
#define NCLS 8

/* h rings: 3 layers x 4 slots, 16384 ELEMENTS per slot.
 * Each element is 8 bytes: {tag:hi32, h_bits:lo32}, written/read with ONE
 * relaxed agent-scope 8B atomic -> the tag travels WITH the data (flag fused
 * into payload; single LLC round trip). Element (k,b) at [k*64 + b]. */
#define SLOT_STRIDE (HD * BB)          /* 16384 elements */
#define LAYER_STRIDE (4 * SLOT_STRIDE) /* 65536 elements */

__device__ __forceinline__ float sigmoidf_(float x) {
    return 1.0f / (1.0f + __expf(-x));
}
__device__ __forceinline__ float tanhf_(float x) {
    return 2.0f / (1.0f + __expf(-2.0f * x)) - 1.0f;
}
__device__ __forceinline__ unsigned long long ld_agent_u64(const unsigned long long* p) {
    return __hip_atomic_load(p, __ATOMIC_RELAXED, __HIP_MEMORY_SCOPE_AGENT);
}
__device__ __forceinline__ void st_agent_u64(unsigned long long* p, unsigned long long v) {
    __hip_atomic_store(p, v, __ATOMIC_RELAXED, __HIP_MEMORY_SCOPE_AGENT);
}

/* ---------------- Kernel 1: xg0T[t][n][b] = (x @ Wih0^T + b0) transposed ---------------- */
#define GBM 128
#define GBN 128
#define GBK 16

__global__ __launch_bounds__(256) void xg0_gemm(const float* __restrict__ x,
                                                const float* __restrict__ Wih0,
                                                const float* __restrict__ b0,
                                                float* __restrict__ xg0T) {
    __shared__ float As[GBK][GBM];
    __shared__ float Bs[GBK][GBN];
    const int m0 = blockIdx.y * GBM;
    const int n0 = blockIdx.x * GBN;
    const int tid = threadIdx.x;
    const int tx = tid & 15;
    const int ty = tid >> 4;
    const int lr = tid >> 1;
    const int lk = (tid & 1) * 8;
    /* permuted A row for logical row m0+lr: b = (m&63), t = (m>>6) */
    const int am = m0 + lr;
    const size_t arow = (size_t)(am & 63) * TT + (am >> 6);
    float acc[8][8] = {};
    for (int k0 = 0; k0 < IN_DIM; k0 += GBK) {
        const float4 a0 = *(const float4*)&x[arow * IN_DIM + k0 + lk];
        const float4 a1 = *(const float4*)&x[arow * IN_DIM + k0 + lk + 4];
        const float4 w0 = *(const float4*)&Wih0[(size_t)(n0 + lr) * IN_DIM + k0 + lk];
        const float4 w1 = *(const float4*)&Wih0[(size_t)(n0 + lr) * IN_DIM + k0 + lk + 4];
        __syncthreads();
        As[lk + 0][lr] = a0.x; As[lk + 1][lr] = a0.y; As[lk + 2][lr] = a0.z; As[lk + 3][lr] = a0.w;
        As[lk + 4][lr] = a1.x; As[lk + 5][lr] = a1.y; As[lk + 6][lr] = a1.z; As[lk + 7][lr] = a1.w;
        Bs[lk + 0][lr] = w0.x; Bs[lk + 1][lr] = w0.y; Bs[lk + 2][lr] = w0.z; Bs[lk + 3][lr] = w0.w;
        Bs[lk + 4][lr] = w1.x; Bs[lk + 5][lr] = w1.y; Bs[lk + 6][lr] = w1.z; Bs[lk + 7][lr] = w1.w;
        __syncthreads();
#pragma unroll
        for (int k = 0; k < GBK; ++k) {
            const float4 av0 = *(const float4*)&As[k][ty * 8];
            const float4 av1 = *(const float4*)&As[k][ty * 8 + 4];
            const float4 bv0 = *(const float4*)&Bs[k][tx * 8];
            const float4 bv1 = *(const float4*)&Bs[k][tx * 8 + 4];
            const float am8[8] = {av0.x, av0.y, av0.z, av0.w, av1.x, av1.y, av1.z, av1.w};
            const float bn8[8] = {bv0.x, bv0.y, bv0.z, bv0.w, bv1.x, bv1.y, bv1.z, bv1.w};
#pragma unroll
            for (int i = 0; i < 8; ++i)
#pragma unroll
                for (int jj = 0; jj < 8; ++jj)
                    acc[i][jj] = fmaf(am8[i], bn8[jj], acc[i][jj]);
        }
    }
    const float4 bias0 = *(const float4*)&b0[n0 + tx * 8];
    const float4 bias1 = *(const float4*)&b0[n0 + tx * 8 + 4];
    const float bia[8] = {bias0.x, bias0.y, bias0.z, bias0.w, bias1.x, bias1.y, bias1.z, bias1.w};
#pragma unroll
    for (int i = 0; i < 8; ++i) {
        const int m = m0 + ty * 8 + i;
        const int t = m >> 6;
        const int bb = m & 63;
#pragma unroll
        for (int jj = 0; jj < 8; ++jj) {
            const int n = n0 + tx * 8 + jj;
            xg0T[((size_t)t * G4H + n) * BB + bb] = acc[i][jj] + bia[jj];
        }
    }
}

/* ---------------- Kernel 2: 3-stage tag-synced LSTM, latency-hidden step pipeline ----------------
 * 192 blocks = 3 layers x 64 blocks. Block owns 4 cells x all 64 b.
 * 512 threads = 8 waves; wave w owns k-chunk [32w, 32w+32).
 * Step schedule (the R5 post-mortem showed the handshake chain, not compute,
 * sets the period):
 *   1. ISSUE own-h[t-1] tagged loads (check deferred)
 *   2. poll+load in-h[t] (layer below ran a full period ahead -> 1 iteration)
 *   3. ih partial compute (~4K cy)  <- own-h loads age under this
 *   4. CHECK own-h tags (data long since arrived), hh partial compute
 *   5. red[p] write, ONE barrier, flag, cell update, tagged h store
 * red[] is parity-double-buffered -> no end-of-step barrier; waves 4-7 run
 * ahead into step t+1 immediately. Weights VGPR-resident (readlane broadcast). */
__global__ __launch_bounds__(512) void lstm_cells(
    const float* __restrict__ xg0T,
    const float* __restrict__ Whh0,
    const float* __restrict__ Wih1, const float* __restrict__ Whh1, const float* __restrict__ b1,
    const float* __restrict__ Wih2, const float* __restrict__ Whh2, const float* __restrict__ b2,
    unsigned long long* __restrict__ ringU, int* __restrict__ flags)
{
    cg::grid_group grid = cg::this_grid();
    const int blk = blockIdx.x;
    const int layer = blk >> 6;        // 0..2
    const int lb = blk & 63;
    const int jbase = lb * 4;
    const int tid = threadIdx.x;
    const int w = tid >> 6;            // wave index 0..7
    const int b = tid & 63;            // lane == batch (compute phase)
    const int kbase = w * 32;

    __shared__ float red[2][16][8][64];   // parity double-buffer, 64 KB

    const float* Wih = (layer == 1) ? Wih1 : Wih2;
    const float* Whh = (layer == 0) ? Whh0 : ((layer == 1) ? Whh1 : Whh2);
    const float* bias = (layer == 1) ? b1 : b2;

    /* ---- stage wave's weight tile into per-lane VGPRs (once) ----
     * lane l holds rows r = l>>2 (of 16), k-sub (l&3)*8 .. +7 of the wave's
     * 32-k chunk. Element (r, q*8+u) is read back via readlane(reg u, r*4+q). */
    float whreg[8];
    float wihreg[8];
    {
        const int r = b >> 2;          // 0..15 = jl*4+g mapping below
        const int jl = r >> 2;
        const int g = r & 3;
        const int kofs = kbase + (b & 3) * 8;
        const float4 h0 = *(const float4*)&Whh[(size_t)(g * HD + jbase + jl) * HD + kofs];
        const float4 h1 = *(const float4*)&Whh[(size_t)(g * HD + jbase + jl) * HD + kofs + 4];
        whreg[0] = h0.x; whreg[1] = h0.y; whreg[2] = h0.z; whreg[3] = h0.w;
        whreg[4] = h1.x; whreg[5] = h1.y; whreg[6] = h1.z; whreg[7] = h1.w;
        if (layer > 0) {
            const float4 i0 = *(const float4*)&Wih[(size_t)(g * HD + jbase + jl) * HD + kofs];
            const float4 i1 = *(const float4*)&Wih[(size_t)(g * HD + jbase + jl) * HD + kofs + 4];
            wihreg[0] = i0.x; wihreg[1] = i0.y; wihreg[2] = i0.z; wihreg[3] = i0.w;
            wihreg[4] = i1.x; wihreg[5] = i1.y; wihreg[6] = i1.z; wihreg[7] = i1.w;
        } else {
#pragma unroll
            for (int u = 0; u < 8; ++u) wihreg[u] = 0.0f;
        }
    }

    /* zero ring (tag=0, h=0) + flags; visible after grid.sync */
    for (int i = blk * 512 + tid; i < 3 * LAYER_STRIDE; i += 192 * 512) ringU[i] = 0ull;
    for (int i = blk * 512 + tid; i < 3 * TT * 64; i += 192 * 512) flags[i] = 0;

    float bs0 = 0.f, bs1 = 0.f, bs2 = 0.f, bs3 = 0.f;
    if (layer > 0 && tid < 256) {
        bs0 = bias[0 * HD + jbase + w]; bs1 = bias[1 * HD + jbase + w];
        bs2 = bias[2 * HD + jbase + w]; bs3 = bias[3 * HD + jbase + w];
    }

    unsigned long long* myU = ringU + (size_t)layer * LAYER_STRIDE;
    const unsigned long long* inU = ringU + (size_t)(layer - 1) * LAYER_STRIDE;

    float c = 0.0f;

    grid.sync();   // ring/flags zeroed, weights staged, all visible

    for (int t = 0; t < TT; ++t) {
        const int p = t & 1;

        /* ---- layer-0 xg prefetch: coalesced from xg0T, issued first ---- */
        float xv0, xv1, xv2, xv3;
        if (layer == 0 && tid < 256) {
            const float* xg = xg0T + ((size_t)t * G4H + jbase + w) * BB + b;
            xv0 = xg[0 * HD * BB]; xv1 = xg[1 * HD * BB];
            xv2 = xg[2 * HD * BB]; xv3 = xg[3 * HD * BB];
        }
        __atomic_signal_fence(__ATOMIC_SEQ_CST);

        /* ---- back-pressure: consumer must have consumed our slot (t-4) ---- */
        if (layer < 2 && t >= 4 && tid < 64) {
            const int* f_nxt = &flags[((layer + 1) * TT + (t - 4)) * 64 + tid];
            for (;;) {
                int ok = __hip_atomic_load(f_nxt, __ATOMIC_RELAXED, __HIP_MEMORY_SCOPE_AGENT);
                if (__all(ok)) break;
                __builtin_amdgcn_s_sleep(2);
            }
        }

        /* ---- (1) ISSUE own h[t-1] tagged loads; tag check deferred ---- */
        const unsigned long long* hp = myU + (size_t)((t + 3) & 3) * SLOT_STRIDE
                                     + (size_t)kbase * BB + b;
        unsigned long long v[32];
#pragma unroll
        for (int u = 0; u < 32; ++u) v[u] = ld_agent_u64(hp + (size_t)u * BB);
        __atomic_signal_fence(__ATOMIC_SEQ_CST);

        float acc[16];

        /* ---- (2)+(3) in-h[t] poll+load, then ih partials (layers 1,2) ---- */
        if (layer > 0) {
            const unsigned long long* gp = inU + (size_t)(t & 3) * SLOT_STRIDE
                                         + (size_t)kbase * BB + b;
            const unsigned wantg = (unsigned)(t + 1);
            unsigned long long v2[32];
            for (;;) {
#pragma unroll
                for (int u = 0; u < 32; ++u) v2[u] = ld_agent_u64(gp + (size_t)u * BB);
                unsigned ok = 1;
#pragma unroll
                for (int u = 0; u < 32; ++u) ok &= ((unsigned)(v2[u] >> 32) == wantg) ? 1u : 0u;
                if (__all(ok != 0)) break;
                __builtin_amdgcn_s_sleep(2);
            }
            float gv[32];
#pragma unroll
            for (int u = 0; u < 32; ++u) gv[u] = __uint_as_float((unsigned)v2[u]);
#pragma unroll
            for (int r = 0; r < 16; ++r) {
                float a = 0.0f;
#pragma unroll
                for (int q = 0; q < 4; ++q) {
#pragma unroll
                    for (int u = 0; u < 8; ++u) {
                        const float ws = __uint_as_float(
                            __builtin_amdgcn_readlane(__float_as_uint(wihreg[u]), r * 4 + q));
                        a = fmaf(ws, gv[q * 8 + u], a);
                    }
                }
                acc[r] = a;
            }
        } else {
#pragma unroll
            for (int r = 0; r < 16; ++r) acc[r] = 0.0f;
        }

        __atomic_signal_fence(__ATOMIC_SEQ_CST);

        /* ---- (4) own-h tag check (loads aged under ih compute), hh partials ---- */
        {
            const unsigned want = (unsigned)t;   // tag written at t-1 is (t-1)+1
            for (;;) {
                unsigned ok = 1;
#pragma unroll
                for (int u = 0; u < 32; ++u) ok &= ((unsigned)(v[u] >> 32) == want) ? 1u : 0u;
                if (__all(ok != 0)) break;
                __builtin_amdgcn_s_sleep(2);
#pragma unroll
                for (int u = 0; u < 32; ++u) v[u] = ld_agent_u64(hp + (size_t)u * BB);
            }
        }
        float hv[32];
#pragma unroll
        for (int u = 0; u < 32; ++u) hv[u] = __uint_as_float((unsigned)v[u]);
#pragma unroll
        for (int r = 0; r < 16; ++r) {
            float a = acc[r];
#pragma unroll
            for (int q = 0; q < 4; ++q) {
#pragma unroll
                for (int u = 0; u < 8; ++u) {
                    const float ws = __uint_as_float(
                        __builtin_amdgcn_readlane(__float_as_uint(whreg[u]), r * 4 + q));
                    a = fmaf(ws, hv[q * 8 + u], a);
                }
            }
            acc[r] = a;
        }

        /* ---- (5) cross-wave reduction into parity buffer, single barrier ---- */
#pragma unroll
        for (int r = 0; r < 16; ++r) red[p][r][w][b] = acc[r];
        __syncthreads();   // the only barrier per step

        /* completion flag (slot-drain for producer): inputs of step t consumed */
        if (tid == 0) {
            __hip_atomic_store(&flags[(layer * TT + t) * 64 + lb], 1,
                               __ATOMIC_RELAXED, __HIP_MEMORY_SCOPE_AGENT);
        }

        /* ---- cell update: waves 0-3, thread = (cell j = w, b); waves 4-7
         * fall through to step t+1's load issue immediately ---- */
        if (tid < 256) {
            float a0, a1, a2, a3;
            if (layer == 0) { a0 = xv0; a1 = xv1; a2 = xv2; a3 = xv3; }
            else            { a0 = bs0; a1 = bs1; a2 = bs2; a3 = bs3; }
#pragma unroll
            for (int ww = 0; ww < 8; ++ww) {
                a0 += red[p][w * 4 + 0][ww][b];
                a1 += red[p][w * 4 + 1][ww][b];
                a2 += red[p][w * 4 + 2][ww][b];
                a3 += red[p][w * 4 + 3][ww][b];
            }
            const float ig = sigmoidf_(a0);
            const float fg = sigmoidf_(a1);
            const float gg = tanhf_(a2);
            const float og = sigmoidf_(a3);
            c = fg * c + ig * gg;
            const float h = og * tanhf_(c);
            const unsigned long long pk =
                ((unsigned long long)(unsigned)(t + 1) << 32) |
                (unsigned long long)__float_as_uint(h);
            st_agent_u64(&myU[(size_t)(t & 3) * SLOT_STRIDE
                              + (size_t)(jbase + w) * BB + b], pk);
        }
        /* no end barrier: red is parity-double-buffered; step t+2's writes to
         * red[p] occur only after barrier(t+1), which waves 0-3 reach after
         * finishing step t's reads. */
    }
}

/* ---------------- Kernel 3: FC head on h2[T-1] (tagged-element layout) ---------------- */
__global__ __launch_bounds__(256) void classifier_k(
    const unsigned long long* __restrict__ ringU,
    const float* __restrict__ W1, const float* __restrict__ bfc1,
    const float* __restrict__ W2, const float* __restrict__ bfc2,
    float* __restrict__ out)
{
    __shared__ float z[BB * 128];
    const unsigned long long* h2T = ringU + 2 * LAYER_STRIDE
                                  + (size_t)((TT - 1) & 3) * SLOT_STRIDE;
    const int tid = threadIdx.x;
    for (int idx = tid; idx < BB * 128; idx += 256) {
        const int bb = idx >> 7;
        const int n = idx & 127;
        float acc = bfc1[n];
        const float* wr = W1 + (size_t)n * HD;
        for (int k = 0; k < HD; ++k) {
            const float hval = __uint_as_float((unsigned)h2T[(size_t)k * BB + bb]);
            acc = fmaf(hval, wr[k], acc);
        }
        z[bb * 128 + n] = fmaxf(acc, 0.0f);
    }
    __syncthreads();
    for (int idx = tid; idx < BB * NCLS; idx += 256) {
        const int bb = idx >> 3;
        const int n = idx & 7;
        float acc = bfc2[n];
        const float* zr = &z[bb * 128];
        const float* wr = W2 + (size_t)n * 128;
        for (int k = 0; k < 128; k += 4) {
            const float4 zv = *(const float4*)&zr[k];
            const float4 wv = *(const float4*)&wr[k];
            acc = fmaf(zv.x, wv.x, acc); acc = fmaf(zv.y, wv.y, acc);
            acc = fmaf(zv.z, wv.z, acc); acc = fmaf(zv.w, wv.w, acc);
        }
        out[idx] = acc;
    }
}

extern "C" void kernel_launch(void* const* d_in, const int* in_sizes, int n_in,
                              void* d_out, int out_size, void* d_ws, size_t ws_size,
                              hipStream_t stream) {
    const float* x    = (const float*)d_in[0];
    const float* Wih0 = (const float*)d_in[1];
    const float* Whh0 = (const float*)d_in[2];
    const float* b0   = (const float*)d_in[3];
    const float* Wih1 = (const float*)d_in[4];
    const float* Whh1 = (const float*)d_in[5];
    const float* b1   = (const float*)d_in[6];
    const float* Wih2 = (const float*)d_in[7];
    const float* Whh2 = (const float*)d_in[8];
    const float* b2   = (const float*)d_in[9];
    const float* W1   = (const float*)d_in[10];
    const float* bfc1 = (const float*)d_in[11];
    const float* W2   = (const float*)d_in[12];
    const float* bfc2 = (const float*)d_in[13];

    float* xg0T = (float*)d_ws;                               // B*T*4H fp32 = 134.2 MB
    unsigned long long* ringU =
        (unsigned long long*)(xg0T + (size_t)BB * TT * G4H);  // 3*4*16384 * 8B = 1.57 MB
    int* flags = (int*)(ringU + 3 * LAYER_STRIDE);            // 3*512*64 ints = 393 KB

    xg0_gemm<<<dim3(G4H / GBN, (BB * TT) / GBM), 256, 0, stream>>>(x, Wih0, b0, xg0T);

    const float* xgc = xg0T;
    unsigned long long* ru = ringU;
    int* fl = flags;
    void* args[] = {
        (void*)&xgc, (void*)&Whh0,
        (void*)&Wih1, (void*)&Whh1, (void*)&b1,
        (void*)&Wih2, (void*)&Whh2, (void*)&b2,
        (void*)&ru, (void*)&fl
    };
    hipLaunchCooperativeKernel((void*)lstm_cells, dim3(192), dim3(512), args, 0, stream);

    classifier_k<<<1, 256, 0, stream>>>(ringU, W1, bfc1, W2, bfc2, (float*)d_out);
}

// Round 7
// 6091.598 us; speedup vs baseline: 1.1653x; 1.1653x over previous
//
#include <hip/hip_runtime.h>
#include <hip/hip_cooperative_groups.h>
#include <cmath>

namespace cg = cooperative_groups;

#define IN_DIM 1024
#define HD 256
#define G4H 1024
#define BB 64
#define TT 512
#define NCLS 8

/* h rings: 3 layers x 4 slots, 16384 ELEMENTS per slot.
 * Each element is 8 bytes: {tag:hi32, h_bits:lo32}, written/read with ONE
 * relaxed agent-scope 8B atomic -> the tag travels WITH the data (flag fused
 * into payload; single LLC round trip). Element (k,b) at [k*64 + b]. */
#define SLOT_STRIDE (HD * BB)          /* 16384 elements */
#define LAYER_STRIDE (4 * SLOT_STRIDE) /* 65536 elements */

__device__ __forceinline__ float sigmoidf_(float x) {
    return 1.0f / (1.0f + __expf(-x));
}
__device__ __forceinline__ float tanhf_(float x) {
    return 2.0f / (1.0f + __expf(-2.0f * x)) - 1.0f;
}
__device__ __forceinline__ unsigned long long ld_agent_u64(const unsigned long long* p) {
    return __hip_atomic_load(p, __ATOMIC_RELAXED, __HIP_MEMORY_SCOPE_AGENT);
}
__device__ __forceinline__ void st_agent_u64(unsigned long long* p, unsigned long long v) {
    __hip_atomic_store(p, v, __ATOMIC_RELAXED, __HIP_MEMORY_SCOPE_AGENT);
}

/* ---------------- Kernel 1: xg0T[t][n][b] = (x @ Wih0^T + b0) transposed ---------------- */
#define GBM 128
#define GBN 128
#define GBK 16

__global__ __launch_bounds__(256) void xg0_gemm(const float* __restrict__ x,
                                                const float* __restrict__ Wih0,
                                                const float* __restrict__ b0,
                                                float* __restrict__ xg0T) {
    __shared__ float As[GBK][GBM];
    __shared__ float Bs[GBK][GBN];
    const int m0 = blockIdx.y * GBM;
    const int n0 = blockIdx.x * GBN;
    const int tid = threadIdx.x;
    const int tx = tid & 15;
    const int ty = tid >> 4;
    const int lr = tid >> 1;
    const int lk = (tid & 1) * 8;
    /* permuted A row for logical row m0+lr: b = (m&63), t = (m>>6) */
    const int am = m0 + lr;
    const size_t arow = (size_t)(am & 63) * TT + (am >> 6);
    float acc[8][8] = {};
    for (int k0 = 0; k0 < IN_DIM; k0 += GBK) {
        const float4 a0 = *(const float4*)&x[arow * IN_DIM + k0 + lk];
        const float4 a1 = *(const float4*)&x[arow * IN_DIM + k0 + lk + 4];
        const float4 w0 = *(const float4*)&Wih0[(size_t)(n0 + lr) * IN_DIM + k0 + lk];
        const float4 w1 = *(const float4*)&Wih0[(size_t)(n0 + lr) * IN_DIM + k0 + lk + 4];
        __syncthreads();
        As[lk + 0][lr] = a0.x; As[lk + 1][lr] = a0.y; As[lk + 2][lr] = a0.z; As[lk + 3][lr] = a0.w;
        As[lk + 4][lr] = a1.x; As[lk + 5][lr] = a1.y; As[lk + 6][lr] = a1.z; As[lk + 7][lr] = a1.w;
        Bs[lk + 0][lr] = w0.x; Bs[lk + 1][lr] = w0.y; Bs[lk + 2][lr] = w0.z; Bs[lk + 3][lr] = w0.w;
        Bs[lk + 4][lr] = w1.x; Bs[lk + 5][lr] = w1.y; Bs[lk + 6][lr] = w1.z; Bs[lk + 7][lr] = w1.w;
        __syncthreads();
#pragma unroll
        for (int k = 0; k < GBK; ++k) {
            const float4 av0 = *(const float4*)&As[k][ty * 8];
            const float4 av1 = *(const float4*)&As[k][ty * 8 + 4];
            const float4 bv0 = *(const float4*)&Bs[k][tx * 8];
            const float4 bv1 = *(const float4*)&Bs[k][tx * 8 + 4];
            const float am8[8] = {av0.x, av0.y, av0.z, av0.w, av1.x, av1.y, av1.z, av1.w};
            const float bn8[8] = {bv0.x, bv0.y, bv0.z, bv0.w, bv1.x, bv1.y, bv1.z, bv1.w};
#pragma unroll
            for (int i = 0; i < 8; ++i)
#pragma unroll
                for (int jj = 0; jj < 8; ++jj)
                    acc[i][jj] = fmaf(am8[i], bn8[jj], acc[i][jj]);
        }
    }
    const float4 bias0 = *(const float4*)&b0[n0 + tx * 8];
    const float4 bias1 = *(const float4*)&b0[n0 + tx * 8 + 4];
    const float bia[8] = {bias0.x, bias0.y, bias0.z, bias0.w, bias1.x, bias1.y, bias1.z, bias1.w};
#pragma unroll
    for (int i = 0; i < 8; ++i) {
        const int m = m0 + ty * 8 + i;
        const int t = m >> 6;
        const int bb = m & 63;
#pragma unroll
        for (int jj = 0; jj < 8; ++jj) {
            const int n = n0 + tx * 8 + jj;
            xg0T[((size_t)t * G4H + n) * BB + bb] = acc[i][jj] + bia[jj];
        }
    }
}

/* ---------------- Kernel 2: 3-stage tag-synced LSTM, slack-filled critical loop ----------------
 * 192 blocks = 3 layers x 64 blocks. Block owns 4 cells x all 64 b.
 * 512 threads = 8 waves; wave w owns k-chunk [32w, 32w+32).
 * SPLIT SCHEDULE (ih does not depend on h[t-1]):
 *   HEAD (critical): poll own-h[t-1] -> hh FMAs into preacc -> red/barrier
 *                    -> cell -> tagged h store.
 *   TAIL (slack, after the store): back-pressure check, gv[t+1] poll + ih
 *   partials -> preacc for the next head; layer 0 prefetches xg[t+1].
 * hv and gv loads live in DIFFERENT phases -> no 128-VGPR conflict (R6's
 * failure). Weights VGPR-resident (readlane broadcast). red parity-buffered,
 * one barrier per step. */
__global__ __launch_bounds__(512) void lstm_cells(
    const float* __restrict__ xg0T,
    const float* __restrict__ Whh0,
    const float* __restrict__ Wih1, const float* __restrict__ Whh1, const float* __restrict__ b1,
    const float* __restrict__ Wih2, const float* __restrict__ Whh2, const float* __restrict__ b2,
    unsigned long long* __restrict__ ringU, int* __restrict__ flags)
{
    cg::grid_group grid = cg::this_grid();
    const int blk = blockIdx.x;
    const int layer = blk >> 6;        // 0..2
    const int lb = blk & 63;
    const int jbase = lb * 4;
    const int tid = threadIdx.x;
    const int w = tid >> 6;            // wave index 0..7
    const int b = tid & 63;            // lane == batch (compute phase)
    const int kbase = w * 32;

    __shared__ float red[2][16][8][64];   // parity double-buffer, 64 KB

    const float* Wih = (layer == 1) ? Wih1 : Wih2;
    const float* Whh = (layer == 0) ? Whh0 : ((layer == 1) ? Whh1 : Whh2);
    const float* bias = (layer == 1) ? b1 : b2;

    /* ---- stage wave's weight tile into per-lane VGPRs (once) ----
     * lane l holds rows r = l>>2 (of 16), k-sub (l&3)*8 .. +7 of the wave's
     * 32-k chunk. Element (r, q*8+u) is read back via readlane(reg u, r*4+q). */
    float whreg[8];
    float wihreg[8];
    {
        const int r = b >> 2;
        const int jl = r >> 2;
        const int g = r & 3;
        const int kofs = kbase + (b & 3) * 8;
        const float4 h0 = *(const float4*)&Whh[(size_t)(g * HD + jbase + jl) * HD + kofs];
        const float4 h1 = *(const float4*)&Whh[(size_t)(g * HD + jbase + jl) * HD + kofs + 4];
        whreg[0] = h0.x; whreg[1] = h0.y; whreg[2] = h0.z; whreg[3] = h0.w;
        whreg[4] = h1.x; whreg[5] = h1.y; whreg[6] = h1.z; whreg[7] = h1.w;
        if (layer > 0) {
            const float4 i0 = *(const float4*)&Wih[(size_t)(g * HD + jbase + jl) * HD + kofs];
            const float4 i1 = *(const float4*)&Wih[(size_t)(g * HD + jbase + jl) * HD + kofs + 4];
            wihreg[0] = i0.x; wihreg[1] = i0.y; wihreg[2] = i0.z; wihreg[3] = i0.w;
            wihreg[4] = i1.x; wihreg[5] = i1.y; wihreg[6] = i1.z; wihreg[7] = i1.w;
        } else {
#pragma unroll
            for (int u = 0; u < 8; ++u) wihreg[u] = 0.0f;
        }
    }

    /* zero ring (tag=0, h=0) + flags; visible after grid.sync */
    for (int i = blk * 512 + tid; i < 3 * LAYER_STRIDE; i += 192 * 512) ringU[i] = 0ull;
    for (int i = blk * 512 + tid; i < 3 * TT * 64; i += 192 * 512) flags[i] = 0;

    float bs0 = 0.f, bs1 = 0.f, bs2 = 0.f, bs3 = 0.f;
    if (layer > 0 && tid < 256) {
        bs0 = bias[0 * HD + jbase + w]; bs1 = bias[1 * HD + jbase + w];
        bs2 = bias[2 * HD + jbase + w]; bs3 = bias[3 * HD + jbase + w];
    }

    unsigned long long* myU = ringU + (size_t)layer * LAYER_STRIDE;
    const unsigned long long* inU = ringU + (size_t)(layer - 1) * LAYER_STRIDE;

    float c = 0.0f;
    float preacc[16];
    float xv0 = 0.f, xv1 = 0.f, xv2 = 0.f, xv3 = 0.f;

    grid.sync();   // ring/flags zeroed, weights staged, all visible

    /* ---- PROLOGUE TAIL: prepare step 0's pre-activation ---- */
    if (layer == 0) {
        if (tid < 256) {
            const float* xg = xg0T + ((size_t)0 * G4H + jbase + w) * BB + b;
            xv0 = xg[0 * HD * BB]; xv1 = xg[1 * HD * BB];
            xv2 = xg[2 * HD * BB]; xv3 = xg[3 * HD * BB];
        }
#pragma unroll
        for (int r = 0; r < 16; ++r) preacc[r] = 0.0f;
    } else {
        const unsigned long long* gp = inU + (size_t)0 * SLOT_STRIDE
                                     + (size_t)kbase * BB + b;
        unsigned long long v2[32];
        for (;;) {
#pragma unroll
            for (int u = 0; u < 32; ++u) v2[u] = ld_agent_u64(gp + (size_t)u * BB);
            unsigned ok = 1;
#pragma unroll
            for (int u = 0; u < 32; ++u) ok &= ((unsigned)(v2[u] >> 32) == 1u) ? 1u : 0u;
            if (__all(ok != 0)) break;
            __builtin_amdgcn_s_sleep(2);
        }
        float gv[32];
#pragma unroll
        for (int u = 0; u < 32; ++u) gv[u] = __uint_as_float((unsigned)v2[u]);
#pragma unroll
        for (int r = 0; r < 16; ++r) {
            float a = 0.0f;
#pragma unroll
            for (int q = 0; q < 4; ++q) {
#pragma unroll
                for (int u = 0; u < 8; ++u) {
                    const float ws = __uint_as_float(
                        __builtin_amdgcn_readlane(__float_as_uint(wihreg[u]), r * 4 + q));
                    a = fmaf(ws, gv[q * 8 + u], a);
                }
            }
            preacc[r] = a;
        }
    }

    for (int t = 0; t < TT; ++t) {
        const int p = t & 1;

        /* ================= HEAD (critical) ================= */

        /* ---- poll own h[t-1]: tagged loads, data-direct (1 RT) ---- */
        float hv[32];
        {
            const unsigned long long* hp = myU + (size_t)((t + 3) & 3) * SLOT_STRIDE
                                         + (size_t)kbase * BB + b;
            const unsigned want = (unsigned)t;   // tag written at t-1 is (t-1)+1
            unsigned long long v[32];
            for (;;) {
#pragma unroll
                for (int u = 0; u < 32; ++u) v[u] = ld_agent_u64(hp + (size_t)u * BB);
                unsigned ok = 1;
#pragma unroll
                for (int u = 0; u < 32; ++u) ok &= ((unsigned)(v[u] >> 32) == want) ? 1u : 0u;
                if (__all(ok != 0)) break;
                __builtin_amdgcn_s_sleep(1);
            }
#pragma unroll
            for (int u = 0; u < 32; ++u) hv[u] = __uint_as_float((unsigned)v[u]);
        }

        /* ---- hh partials accumulate into preacc (ih already included) ---- */
#pragma unroll
        for (int r = 0; r < 16; ++r) {
            float a = preacc[r];
#pragma unroll
            for (int q = 0; q < 4; ++q) {
#pragma unroll
                for (int u = 0; u < 8; ++u) {
                    const float ws = __uint_as_float(
                        __builtin_amdgcn_readlane(__float_as_uint(whreg[u]), r * 4 + q));
                    a = fmaf(ws, hv[q * 8 + u], a);
                }
            }
            preacc[r] = a;
        }

        /* ---- cross-wave reduction into parity buffer, single barrier ---- */
#pragma unroll
        for (int r = 0; r < 16; ++r) red[p][r][w][b] = preacc[r];
        __syncthreads();

        /* completion flag (slot-drain for producer): inputs of step t consumed */
        if (tid == 0) {
            __hip_atomic_store(&flags[(layer * TT + t) * 64 + lb], 1,
                               __ATOMIC_RELAXED, __HIP_MEMORY_SCOPE_AGENT);
        }

        /* ---- cell update: waves 0-3, thread = (cell j = w, b) ---- */
        if (tid < 256) {
            float a0, a1, a2, a3;
            if (layer == 0) { a0 = xv0; a1 = xv1; a2 = xv2; a3 = xv3; }
            else            { a0 = bs0; a1 = bs1; a2 = bs2; a3 = bs3; }
#pragma unroll
            for (int ww = 0; ww < 8; ++ww) {
                a0 += red[p][w * 4 + 0][ww][b];
                a1 += red[p][w * 4 + 1][ww][b];
                a2 += red[p][w * 4 + 2][ww][b];
                a3 += red[p][w * 4 + 3][ww][b];
            }
            const float ig = sigmoidf_(a0);
            const float fg = sigmoidf_(a1);
            const float gg = tanhf_(a2);
            const float og = sigmoidf_(a3);
            c = fg * c + ig * gg;
            const float h = og * tanhf_(c);
            const unsigned long long pk =
                ((unsigned long long)(unsigned)(t + 1) << 32) |
                (unsigned long long)__float_as_uint(h);
            st_agent_u64(&myU[(size_t)(t & 3) * SLOT_STRIDE
                              + (size_t)(jbase + w) * BB + b], pk);
        }

        /* ================= TAIL (slack, prepares t+1) ================= */
        if (t + 1 < TT) {
            /* back-pressure for step t+1's store: consumer drained slot (t+1)-4 */
            if (layer < 2 && t + 1 >= 4 && tid < 64) {
                const int* f_nxt = &flags[((layer + 1) * TT + (t - 3)) * 64 + tid];
                for (;;) {
                    int ok = __hip_atomic_load(f_nxt, __ATOMIC_RELAXED, __HIP_MEMORY_SCOPE_AGENT);
                    if (__all(ok)) break;
                    __builtin_amdgcn_s_sleep(2);
                }
            }

            if (layer == 0) {
                if (tid < 256) {
                    const float* xg = xg0T + ((size_t)(t + 1) * G4H + jbase + w) * BB + b;
                    xv0 = xg[0 * HD * BB]; xv1 = xg[1 * HD * BB];
                    xv2 = xg[2 * HD * BB]; xv3 = xg[3 * HD * BB];
                }
#pragma unroll
                for (int r = 0; r < 16; ++r) preacc[r] = 0.0f;
            } else {
                /* poll in-h[t+1] (slot lag makes this non-blocking), ih partials */
                const unsigned long long* gp = inU + (size_t)((t + 1) & 3) * SLOT_STRIDE
                                             + (size_t)kbase * BB + b;
                const unsigned wantg = (unsigned)(t + 2);
                unsigned long long v2[32];
                for (;;) {
#pragma unroll
                    for (int u = 0; u < 32; ++u) v2[u] = ld_agent_u64(gp + (size_t)u * BB);
                    unsigned ok = 1;
#pragma unroll
                    for (int u = 0; u < 32; ++u) ok &= ((unsigned)(v2[u] >> 32) == wantg) ? 1u : 0u;
                    if (__all(ok != 0)) break;
                    __builtin_amdgcn_s_sleep(2);
                }
                float gv[32];
#pragma unroll
                for (int u = 0; u < 32; ++u) gv[u] = __uint_as_float((unsigned)v2[u]);
#pragma unroll
                for (int r = 0; r < 16; ++r) {
                    float a = 0.0f;
#pragma unroll
                    for (int q = 0; q < 4; ++q) {
#pragma unroll
                        for (int u = 0; u < 8; ++u) {
                            const float ws = __uint_as_float(
                                __builtin_amdgcn_readlane(__float_as_uint(wihreg[u]), r * 4 + q));
                            a = fmaf(ws, gv[q * 8 + u], a);
                        }
                    }
                    preacc[r] = a;
                }
            }
        }
    }
}

/* ---------------- Kernel 3: FC head on h2[T-1] (tagged-element layout) ---------------- */
__global__ __launch_bounds__(256) void classifier_k(
    const unsigned long long* __restrict__ ringU,
    const float* __restrict__ W1, const float* __restrict__ bfc1,
    const float* __restrict__ W2, const float* __restrict__ bfc2,
    float* __restrict__ out)
{
    __shared__ float z[BB * 128];
    const unsigned long long* h2T = ringU + 2 * LAYER_STRIDE
                                  + (size_t)((TT - 1) & 3) * SLOT_STRIDE;
    const int tid = threadIdx.x;
    for (int idx = tid; idx < BB * 128; idx += 256) {
        const int bb = idx >> 7;
        const int n = idx & 127;
        float acc = bfc1[n];
        const float* wr = W1 + (size_t)n * HD;
        for (int k = 0; k < HD; ++k) {
            const float hval = __uint_as_float((unsigned)h2T[(size_t)k * BB + bb]);
            acc = fmaf(hval, wr[k], acc);
        }
        z[bb * 128 + n] = fmaxf(acc, 0.0f);
    }
    __syncthreads();
    for (int idx = tid; idx < BB * NCLS; idx += 256) {
        const int bb = idx >> 3;
        const int n = idx & 7;
        float acc = bfc2[n];
        const float* zr = &z[bb * 128];
        const float* wr = W2 + (size_t)n * 128;
        for (int k = 0; k < 128; k += 4) {
            const float4 zv = *(const float4*)&zr[k];
            const float4 wv = *(const float4*)&wr[k];
            acc = fmaf(zv.x, wv.x, acc); acc = fmaf(zv.y, wv.y, acc);
            acc = fmaf(zv.z, wv.z, acc); acc = fmaf(zv.w, wv.w, acc);
        }
        out[idx] = acc;
    }
}

extern "C" void kernel_launch(void* const* d_in, const int* in_sizes, int n_in,
                              void* d_out, int out_size, void* d_ws, size_t ws_size,
                              hipStream_t stream) {
    const float* x    = (const float*)d_in[0];
    const float* Wih0 = (const float*)d_in[1];
    const float* Whh0 = (const float*)d_in[2];
    const float* b0   = (const float*)d_in[3];
    const float* Wih1 = (const float*)d_in[4];
    const float* Whh1 = (const float*)d_in[5];
    const float* b1   = (const float*)d_in[6];
    const float* Wih2 = (const float*)d_in[7];
    const float* Whh2 = (const float*)d_in[8];
    const float* b2   = (const float*)d_in[9];
    const float* W1   = (const float*)d_in[10];
    const float* bfc1 = (const float*)d_in[11];
    const float* W2   = (const float*)d_in[12];
    const float* bfc2 = (const float*)d_in[13];

    float* xg0T = (float*)d_ws;                               // B*T*4H fp32 = 134.2 MB
    unsigned long long* ringU =
        (unsigned long long*)(xg0T + (size_t)BB * TT * G4H);  // 3*4*16384 * 8B = 1.57 MB
    int* flags = (int*)(ringU + 3 * LAYER_STRIDE);            // 3*512*64 ints = 393 KB

    xg0_gemm<<<dim3(G4H / GBN, (BB * TT) / GBM), 256, 0, stream>>>(x, Wih0, b0, xg0T);

    const float* xgc = xg0T;
    unsigned long long* ru = ringU;
    int* fl = flags;
    void* args[] = {
        (void*)&xgc, (void*)&Whh0,
        (void*)&Wih1, (void*)&Whh1, (void*)&b1,
        (void*)&Wih2, (void*)&Whh2, (void*)&b2,
        (void*)&ru, (void*)&fl
    };
    hipLaunchCooperativeKernel((void*)lstm_cells, dim3(192), dim3(512), args, 0, stream);

    classifier_k<<<1, 256, 0, stream>>>(ringU, W1, bfc1, W2, bfc2, (float*)d_out);
}